// Round 1
// baseline (660.846 us; speedup 1.0000x reference)
//
#include <hip/hip_runtime.h>
#include <hip/hip_bf16.h>

#define D_MODEL 1024
#define INNER   2048
#define NPROJ   4096   // 2*INNER
#define D_STATE 16
#define BSZ     2
#define LSEQ    1024
#define MROWS   (BSZ*LSEQ)  // 2048

// NT GEMM: C[M,N] = A[M,K] * B[N,K]^T, all row-major f32.
template<int N, int K>
__global__ __launch_bounds__(256) void gemm_nt(const float* __restrict__ A,
                                               const float* __restrict__ B,
                                               float* __restrict__ C) {
    const int BK = 16;
    __shared__ __align__(16) float As[BK][68];
    __shared__ __align__(16) float Bs[BK][68];
    int tid = threadIdx.x;
    int tx = tid & 15, ty = tid >> 4;
    int m0 = blockIdx.y * 64;
    int n0 = blockIdx.x * 64;
    float acc[4][4] = {};
    int lr = tid >> 2;        // 0..63 row within tile
    int lk = (tid & 3) * 4;   // k sub-offset

    for (int k0 = 0; k0 < K; k0 += BK) {
        float4 av = *reinterpret_cast<const float4*>(&A[(size_t)(m0 + lr) * K + k0 + lk]);
        float4 bv = *reinterpret_cast<const float4*>(&B[(size_t)(n0 + lr) * K + k0 + lk]);
        As[lk + 0][lr] = av.x; As[lk + 1][lr] = av.y; As[lk + 2][lr] = av.z; As[lk + 3][lr] = av.w;
        Bs[lk + 0][lr] = bv.x; Bs[lk + 1][lr] = bv.y; Bs[lk + 2][lr] = bv.z; Bs[lk + 3][lr] = bv.w;
        __syncthreads();
#pragma unroll
        for (int k = 0; k < BK; ++k) {
            float4 a = *reinterpret_cast<const float4*>(&As[k][ty * 4]);
            float4 b = *reinterpret_cast<const float4*>(&Bs[k][tx * 4]);
            float ar[4] = {a.x, a.y, a.z, a.w};
            float br[4] = {b.x, b.y, b.z, b.w};
#pragma unroll
            for (int i = 0; i < 4; i++)
#pragma unroll
                for (int j = 0; j < 4; j++)
                    acc[i][j] += ar[i] * br[j];
        }
        __syncthreads();
    }
#pragma unroll
    for (int i = 0; i < 4; i++) {
        float4 o = make_float4(acc[i][0], acc[i][1], acc[i][2], acc[i][3]);
        *reinterpret_cast<float4*>(&C[(size_t)(m0 + ty * 4 + i) * N + n0 + tx * 4]) = o;
    }
}

// Fused depthwise conv(4) + sigmoid + selective-scan + gate.
// Block: 256 threads = 16 channels x 16 states. Grid: BSZ * (INNER/16).
__global__ __launch_bounds__(256) void scan_kernel(
    const float* __restrict__ xp,      // (B, L, 4096) interleaved u/gate
    const float* __restrict__ conv_w,  // (INNER, 4)
    const float* __restrict__ conv_b,  // (INNER,)
    const float* __restrict__ Aa,      // (INNER, 16)
    const float* __restrict__ Bp,      // (INNER, 16)
    const float* __restrict__ Cp,      // (INNER, 16)
    float* __restrict__ yg)            // (B, L, INNER)
{
    const int CH = 16;
    const int CHUNK = 64;
    __shared__ __align__(16) float sx[CHUNK][2 * CH];  // [l][2*CH] interleaved u,gate

    int tid = threadIdx.x;
    int c = tid >> 4;   // channel within block
    int s = tid & 15;   // state index
    int b  = blockIdx.x / (INNER / CH);
    int nb = (blockIdx.x % (INNER / CH)) * CH;
    int n = nb + c;

    float w0 = conv_w[n * 4 + 0], w1 = conv_w[n * 4 + 1];
    float w2 = conv_w[n * 4 + 2], w3 = conv_w[n * 4 + 3];
    float cb = conv_b[n];
    float An = Aa[n * 16 + s], Bn = Bp[n * 16 + s], Cn = Cp[n * 16 + s];

    float u0 = 0.f, u1 = 0.f, u2 = 0.f;
    float st = 0.f;
    const float* xpb = xp + (size_t)b * LSEQ * NPROJ + 2 * nb;
    float* ygb = yg + (size_t)b * LSEQ * INNER + nb;

    for (int l0 = 0; l0 < LSEQ; l0 += CHUNK) {
        __syncthreads();
        {
            // cooperative load: CHUNK rows x 32 floats = 2048 floats; 8 per thread
            int idx = tid * 8;
            int lrr = idx >> 5;
            int col = idx & 31;
            const float4* src = reinterpret_cast<const float4*>(
                xpb + (size_t)(l0 + lrr) * NPROJ + col);
            float4 v0 = src[0];
            float4 v1 = src[1];
            *reinterpret_cast<float4*>(&sx[lrr][col]) = v0;
            *reinterpret_cast<float4*>(&sx[lrr][col + 4]) = v1;
        }
        __syncthreads();
#pragma unroll 8
        for (int l = 0; l < CHUNK; ++l) {
            float ul = sx[l][2 * c];
            float gl = sx[l][2 * c + 1];
            float xc = cb + w0 * u0 + w1 * u1 + w2 * u2 + w3 * ul;
            u0 = u1; u1 = u2; u2 = ul;
            float delta = 1.f / (1.f + __expf(-xc));
            st = (An * delta) * st + Bn * (delta * xc);
            float y = st * Cn;
            y += __shfl_xor(y, 1);
            y += __shfl_xor(y, 2);
            y += __shfl_xor(y, 4);
            y += __shfl_xor(y, 8);
            if (s == 0) {
                float g = 1.f / (1.f + __expf(-gl));
                ygb[(size_t)(l0 + l) * INNER + c] = y * g;
            }
        }
    }
}

extern "C" void kernel_launch(void* const* d_in, const int* in_sizes, int n_in,
                              void* d_out, int out_size, void* d_ws, size_t ws_size,
                              hipStream_t stream) {
    const float* x      = (const float*)d_in[0];
    const float* W_in   = (const float*)d_in[1];
    const float* conv_w = (const float*)d_in[2];
    const float* conv_b = (const float*)d_in[3];
    const float* A      = (const float*)d_in[4];
    const float* Bp     = (const float*)d_in[5];
    const float* Cp     = (const float*)d_in[6];
    // d_in[7] = D_param, unused by the reference forward
    const float* W_out  = (const float*)d_in[8];
    float* out = (float*)d_out;

    float* xp  = (float*)d_ws;                  // MROWS * NPROJ f32 = 32 MB
    float* ygd = xp + (size_t)MROWS * NPROJ;    // MROWS * INNER f32 = 16 MB

    dim3 blk(256);
    gemm_nt<NPROJ, D_MODEL><<<dim3(NPROJ / 64, MROWS / 64), blk, 0, stream>>>(x, W_in, xp);
    scan_kernel<<<dim3(BSZ * (INNER / 16)), blk, 0, stream>>>(xp, conv_w, conv_b, A, Bp, Cp, ygd);
    gemm_nt<D_MODEL, INNER><<<dim3(D_MODEL / 64, MROWS / 64), blk, 0, stream>>>(ygd, W_out, out);
}

// Round 3
// 433.844 us; speedup vs baseline: 1.5232x; 1.5232x over previous
//
#include <hip/hip_runtime.h>
#include <hip/hip_bf16.h>

#define D_MODEL 1024
#define INNER   2048
#define NPROJ   4096   // 2*INNER
#define D_STATE 16
#define BSZ     2
#define LSEQ    1024
#define MROWS   (BSZ*LSEQ)  // 2048

#define CHUNK 32
#define WARM  48
#define NCHK  (LSEQ / CHUNK)   // 32

// NT GEMM: C[M,N] = A[M,K] * B[N,K]^T, all row-major f32.
// BM x 128 tile, 256 threads, (BM/16) x 8 micro-tile per thread.
template<int BM, int N, int K>
__global__ __launch_bounds__(256) void gemm_nt(const float* __restrict__ A,
                                               const float* __restrict__ Bm,
                                               float* __restrict__ C) {
    const int BN = 128, BK = 16;
    const int MR = BM / 16;
    __shared__ __align__(16) float As[BK][BM + 4];
    __shared__ __align__(16) float Bs[BK][BN + 4];
    int tid = threadIdx.x;
    int m0 = blockIdx.y * BM, n0 = blockIdx.x * BN;
    int ty = tid >> 4, tx = tid & 15;
    float acc[MR][8] = {};

    for (int k0 = 0; k0 < K; k0 += BK) {
#pragma unroll
        for (int it = 0; it < (BM * 4) / 256; ++it) {
            int i = tid + it * 256;
            int r = i >> 2, c = (i & 3) * 4;
            float4 v = *reinterpret_cast<const float4*>(&A[(size_t)(m0 + r) * K + k0 + c]);
            As[c + 0][r] = v.x; As[c + 1][r] = v.y; As[c + 2][r] = v.z; As[c + 3][r] = v.w;
        }
#pragma unroll
        for (int it = 0; it < 2; ++it) {
            int i = tid + it * 256;
            int r = i >> 2, c = (i & 3) * 4;
            float4 v = *reinterpret_cast<const float4*>(&Bm[(size_t)(n0 + r) * K + k0 + c]);
            Bs[c + 0][r] = v.x; Bs[c + 1][r] = v.y; Bs[c + 2][r] = v.z; Bs[c + 3][r] = v.w;
        }
        __syncthreads();
#pragma unroll
        for (int k = 0; k < BK; ++k) {
            float a[MR], b[8];
            {
                float4 v0 = *reinterpret_cast<const float4*>(&Bs[k][tx * 8]);
                float4 v1 = *reinterpret_cast<const float4*>(&Bs[k][tx * 8 + 4]);
                b[0]=v0.x; b[1]=v0.y; b[2]=v0.z; b[3]=v0.w;
                b[4]=v1.x; b[5]=v1.y; b[6]=v1.z; b[7]=v1.w;
            }
#pragma unroll
            for (int i = 0; i < MR; i += 4) {
                float4 v = *reinterpret_cast<const float4*>(&As[k][ty * MR + i]);
                a[i]=v.x; a[i+1]=v.y; a[i+2]=v.z; a[i+3]=v.w;
            }
#pragma unroll
            for (int i = 0; i < MR; i++)
#pragma unroll
                for (int j = 0; j < 8; j++)
                    acc[i][j] += a[i] * b[j];
        }
        __syncthreads();
    }
#pragma unroll
    for (int i = 0; i < MR; i++) {
        size_t row = (size_t)(m0 + ty * MR + i) * N + n0 + tx * 8;
        *reinterpret_cast<float4*>(&C[row]) =
            make_float4(acc[i][0], acc[i][1], acc[i][2], acc[i][3]);
        *reinterpret_cast<float4*>(&C[row + 4]) =
            make_float4(acc[i][4], acc[i][5], acc[i][6], acc[i][7]);
    }
}

// Chunk-parallel fused conv + sigmoid + scan + gate.
// Thread = (b, channel, L-chunk); 16 states in registers; warm-up of up to 48
// steps re-establishes the (exponentially forgotten) state at chunk boundary.
__global__ __launch_bounds__(256) void scan_kernel(
    const float* __restrict__ xp,      // (B, L, 4096) interleaved u/gate
    const float* __restrict__ conv_w,  // (INNER, 4)
    const float* __restrict__ conv_b,  // (INNER,)
    const float* __restrict__ Aa,      // (INNER, 16)
    const float* __restrict__ Bp,      // (INNER, 16)
    const float* __restrict__ Cp,      // (INNER, 16)
    float* __restrict__ yg)            // (B, L, INNER)
{
    const int NB = INNER / 256;  // 8
    int tid = threadIdx.x;
    int bi = blockIdx.x;
    int b  = bi / (NCHK * NB);
    int r  = bi % (NCHK * NB);
    int ch = r / NB;
    int n  = (r % NB) * 256 + tid;

    float4 w = *reinterpret_cast<const float4*>(&conv_w[n * 4]);
    float cb = conv_b[n];
    float An[16], Bn[16], Cn[16], st[16];
#pragma unroll
    for (int i = 0; i < 16; i += 4) {
        float4 va = *reinterpret_cast<const float4*>(&Aa[n * 16 + i]);
        float4 vb = *reinterpret_cast<const float4*>(&Bp[n * 16 + i]);
        float4 vc = *reinterpret_cast<const float4*>(&Cp[n * 16 + i]);
        An[i]=va.x; An[i+1]=va.y; An[i+2]=va.z; An[i+3]=va.w;
        Bn[i]=vb.x; Bn[i+1]=vb.y; Bn[i+2]=vb.z; Bn[i+3]=vb.w;
        Cn[i]=vc.x; Cn[i+1]=vc.y; Cn[i+2]=vc.z; Cn[i+3]=vc.w;
    }
#pragma unroll
    for (int s = 0; s < 16; ++s) st[s] = 0.f;

    int out0 = ch * CHUNK;
    int lstart = (out0 >= WARM) ? (out0 - WARM) : 0;   // clamp: no OOB
    float u0 = 0.f, u1 = 0.f, u2 = 0.f;
    const float* xb = xp + (size_t)b * LSEQ * NPROJ;
    float* yb = yg + (size_t)b * LSEQ * INNER;

    // warm-up: state reconstruction, no outputs
    for (int l = lstart; l < out0; l += 8) {
        float uv[8];
#pragma unroll
        for (int i = 0; i < 8; ++i)
            uv[i] = xb[(size_t)(l + i) * NPROJ + 2 * n];
#pragma unroll
        for (int i = 0; i < 8; ++i) {
            float ul = uv[i];
            float xc = cb + w.x * u0 + w.y * u1 + w.z * u2 + w.w * ul;
            u0 = u1; u1 = u2; u2 = ul;
            float d = 1.f / (1.f + __expf(-xc));
            float dxc = d * xc;
#pragma unroll
            for (int s = 0; s < 16; ++s)
                st[s] = (An[s] * d) * st[s] + Bn[s] * dxc;
        }
    }
    // main: outputs
    for (int lt = 0; lt < CHUNK; lt += 8) {
        float uv[8], gv[8];
#pragma unroll
        for (int i = 0; i < 8; ++i) {
            float2 ug = *reinterpret_cast<const float2*>(
                &xb[(size_t)(out0 + lt + i) * NPROJ + 2 * n]);
            uv[i] = ug.x; gv[i] = ug.y;
        }
#pragma unroll
        for (int i = 0; i < 8; ++i) {
            float ul = uv[i];
            float xc = cb + w.x * u0 + w.y * u1 + w.z * u2 + w.w * ul;
            u0 = u1; u1 = u2; u2 = ul;
            float d = 1.f / (1.f + __expf(-xc));
            float dxc = d * xc;
            float y0 = 0.f, y1 = 0.f, y2 = 0.f, y3 = 0.f;
#pragma unroll
            for (int s = 0; s < 16; s += 4) {
                st[s + 0] = (An[s + 0] * d) * st[s + 0] + Bn[s + 0] * dxc;
                st[s + 1] = (An[s + 1] * d) * st[s + 1] + Bn[s + 1] * dxc;
                st[s + 2] = (An[s + 2] * d) * st[s + 2] + Bn[s + 2] * dxc;
                st[s + 3] = (An[s + 3] * d) * st[s + 3] + Bn[s + 3] * dxc;
                y0 += st[s + 0] * Cn[s + 0];
                y1 += st[s + 1] * Cn[s + 1];
                y2 += st[s + 2] * Cn[s + 2];
                y3 += st[s + 3] * Cn[s + 3];
            }
            float y = (y0 + y1) + (y2 + y3);
            float g = 1.f / (1.f + __expf(-gv[i]));
            yb[(size_t)(out0 + lt + i) * INNER + n] = y * g;
        }
    }
}

extern "C" void kernel_launch(void* const* d_in, const int* in_sizes, int n_in,
                              void* d_out, int out_size, void* d_ws, size_t ws_size,
                              hipStream_t stream) {
    const float* x      = (const float*)d_in[0];
    const float* W_in   = (const float*)d_in[1];
    const float* conv_w = (const float*)d_in[2];
    const float* conv_b = (const float*)d_in[3];
    const float* A      = (const float*)d_in[4];
    const float* Bp     = (const float*)d_in[5];
    const float* Cp     = (const float*)d_in[6];
    // d_in[7] = D_param, unused by the reference forward
    const float* W_out  = (const float*)d_in[8];
    float* out = (float*)d_out;

    float* xp  = (float*)d_ws;                  // MROWS * NPROJ f32 = 32 MB
    float* ygd = xp + (size_t)MROWS * NPROJ;    // MROWS * INNER f32 = 16 MB

    dim3 blk(256);
    gemm_nt<128, NPROJ, D_MODEL><<<dim3(NPROJ / 128, MROWS / 128), blk, 0, stream>>>(x, W_in, xp);
    scan_kernel<<<dim3(BSZ * NCHK * (INNER / 256)), blk, 0, stream>>>(xp, conv_w, conv_b, A, Bp, Cp, ygd);
    gemm_nt<64, D_MODEL, INNER><<<dim3(D_MODEL / 128, MROWS / 64), blk, 0, stream>>>(ygd, W_out, out);
}

// Round 4
// 159.335 us; speedup vs baseline: 4.1475x; 2.7228x over previous
//
#include <hip/hip_runtime.h>
#include <hip/hip_bf16.h>

#define D_MODEL 1024
#define INNER   2048
#define NPROJ   4096   // 2*INNER
#define BSZ     2
#define LSEQ    1024
#define MROWS   (BSZ*LSEQ)  // 2048

#define CHUNK 32
#define WARM  48
#define NCHK  (LSEQ / CHUNK)   // 32

using short8   = __attribute__((ext_vector_type(8))) short;
using ushort8  = __attribute__((ext_vector_type(8))) unsigned short;
using ushort4v = __attribute__((ext_vector_type(4))) unsigned short;
using f32x4    = __attribute__((ext_vector_type(4))) float;

__device__ __forceinline__ unsigned short tobf(float x) {
    return (unsigned short)(__builtin_bit_cast(unsigned, x) >> 16);
}
__device__ __forceinline__ float frombf(unsigned short h) {
    return __builtin_bit_cast(float, ((unsigned)h) << 16);
}
__device__ __forceinline__ void glds16(const void* g, void* l) {
    __builtin_amdgcn_global_load_lds((const __attribute__((address_space(1))) void*)g,
                                     (__attribute__((address_space(3))) void*)l, 16, 0, 0);
}

// split f32 -> bf16 hi + bf16 lo (residual)
__global__ __launch_bounds__(256) void splitbf_k(const float* __restrict__ in,
                                                 unsigned short* __restrict__ hi,
                                                 unsigned short* __restrict__ lo, int n) {
    int i = (blockIdx.x * 256 + threadIdx.x) * 4;
    if (i >= n) return;
    float4 v = *reinterpret_cast<const float4*>(&in[i]);
    float f[4] = {v.x, v.y, v.z, v.w};
    ushort4v h, l;
#pragma unroll
    for (int j = 0; j < 4; ++j) {
        h[j] = tobf(f[j]);
        l[j] = tobf(f[j] - frombf(h[j]));
    }
    *reinterpret_cast<ushort4v*>(&hi[i]) = h;
    *reinterpret_cast<ushort4v*>(&lo[i]) = l;
}

// C[M,N] = A[M,K] * B[N,K]^T via bf16x3 MFMA (hi*hi + hi*lo + lo*hi).
// 256 thr = 4 waves (2x2), wave tile (BM/2)x(BN/2), 16x16x32 fragments, BK=32.
// B (and A if !CONVA) staged by global_load_lds from pre-split bf16;
// if CONVA, A is f32 converted in-register during staging.
template<int BM, int BN, int M, int N, int K, bool CONVA>
__global__ __launch_bounds__(256, 2) void gemm_mfma(
    const float* __restrict__ Af,
    const unsigned short* __restrict__ Agh, const unsigned short* __restrict__ Agl,
    const unsigned short* __restrict__ Bgh, const unsigned short* __restrict__ Bgl,
    float* __restrict__ C)
{
    constexpr int BK = 32;
    constexpr int NT = K / BK;
    constexpr int FM = BM / 32;
    constexpr int FN = BN / 32;
    __shared__ unsigned short Ah[2][BM][BK], Al[2][BM][BK];
    __shared__ unsigned short Bh[2][BN][BK], Bl[2][BN][BK];

    const int tid = threadIdx.x;
    const int wid = tid >> 6, lane = tid & 63;
    const int lm = lane & 15, lk = lane >> 4;
    const int m0 = blockIdx.y * BM, n0 = blockIdx.x * BN;
    const int wm = (wid >> 1) * (BM / 2), wn = (wid & 1) * (BN / 2);

    f32x4 acc[FM][FN] = {};
    float areg[16];

    auto stage_glds_tile = [&](const unsigned short* __restrict__ src, unsigned short* dst,
                               int rows, int rb, int k0) {
        const int ncalls = rows >> 4;  // 16 rows (1024 B) per wave-call
        for (int c = wid; c < ncalls; c += 4) {
            const unsigned short* g =
                src + (size_t)(rb + c * 16 + (lane >> 2)) * K + k0 + (lane & 3) * 8;
            glds16(g, dst + c * 512);
        }
    };
    auto stageB = [&](int t, int b) {
        stage_glds_tile(Bgh, &Bh[b][0][0], BN, n0, t * BK);
        stage_glds_tile(Bgl, &Bl[b][0][0], BN, n0, t * BK);
    };
    auto stageA_glds = [&](int t, int b) {
        stage_glds_tile(Agh, &Ah[b][0][0], BM, m0, t * BK);
        stage_glds_tile(Agl, &Al[b][0][0], BM, m0, t * BK);
    };
    auto stageA_load = [&](int t) {
        const float* p = Af + (size_t)(m0 + (tid >> 1)) * K + t * BK + (tid & 1) * 16;
#pragma unroll
        for (int i = 0; i < 4; ++i) {
            float4 v = *reinterpret_cast<const float4*>(p + i * 4);
            areg[i * 4 + 0] = v.x; areg[i * 4 + 1] = v.y;
            areg[i * 4 + 2] = v.z; areg[i * 4 + 3] = v.w;
        }
    };
    auto stageA_write = [&](int b) {
        int r = tid >> 1, c0 = (tid & 1) * 16;
        ushort8 h[2], l8[2];
#pragma unroll
        for (int i = 0; i < 16; ++i) {
            unsigned short hh = tobf(areg[i]);
            unsigned short ll = tobf(areg[i] - frombf(hh));
            h[i >> 3][i & 7] = hh; l8[i >> 3][i & 7] = ll;
        }
        *reinterpret_cast<ushort8*>(&Ah[b][r][c0])     = h[0];
        *reinterpret_cast<ushort8*>(&Ah[b][r][c0 + 8]) = h[1];
        *reinterpret_cast<ushort8*>(&Al[b][r][c0])     = l8[0];
        *reinterpret_cast<ushort8*>(&Al[b][r][c0 + 8]) = l8[1];
    };
    auto compute = [&](int b) {
        short8 ah[FM], al[FM], bh[FN], bl[FN];
#pragma unroll
        for (int i = 0; i < FM; ++i) {
            ah[i] = *reinterpret_cast<const short8*>(&Ah[b][wm + i * 16 + lm][lk * 8]);
            al[i] = *reinterpret_cast<const short8*>(&Al[b][wm + i * 16 + lm][lk * 8]);
        }
#pragma unroll
        for (int j = 0; j < FN; ++j) {
            bh[j] = *reinterpret_cast<const short8*>(&Bh[b][wn + j * 16 + lm][lk * 8]);
            bl[j] = *reinterpret_cast<const short8*>(&Bl[b][wn + j * 16 + lm][lk * 8]);
        }
#pragma unroll
        for (int i = 0; i < FM; ++i)
#pragma unroll
            for (int j = 0; j < FN; ++j) {
                acc[i][j] = __builtin_amdgcn_mfma_f32_16x16x32_bf16(ah[i], bh[j], acc[i][j], 0, 0, 0);
                acc[i][j] = __builtin_amdgcn_mfma_f32_16x16x32_bf16(ah[i], bl[j], acc[i][j], 0, 0, 0);
                acc[i][j] = __builtin_amdgcn_mfma_f32_16x16x32_bf16(al[i], bh[j], acc[i][j], 0, 0, 0);
            }
    };

    // prologue: stage tile 0 into buf 0
    stageB(0, 0);
    if constexpr (CONVA) { stageA_load(0); stageA_write(0); } else { stageA_glds(0, 0); }
    __syncthreads();

    int buf = 0;
    for (int t = 0; t < NT; ++t) {
        if (t + 1 < NT) {
            stageB(t + 1, buf ^ 1);
            if constexpr (CONVA) stageA_load(t + 1); else stageA_glds(t + 1, buf ^ 1);
        }
        compute(buf);
        if constexpr (CONVA) { if (t + 1 < NT) stageA_write(buf ^ 1); }
        __syncthreads();
        buf ^= 1;
    }

#pragma unroll
    for (int i = 0; i < FM; ++i)
#pragma unroll
        for (int j = 0; j < FN; ++j)
#pragma unroll
            for (int r = 0; r < 4; ++r) {
                int row = m0 + wm + i * 16 + lk * 4 + r;
                int col = n0 + wn + j * 16 + lm;
                C[(size_t)row * N + col] = acc[i][j][r];
            }
}

// Chunk-parallel fused conv + sigmoid + scan + gate; emits yg as bf16 hi/lo.
__global__ __launch_bounds__(256) void scan_kernel(
    const float* __restrict__ xp,      // (B, L, 4096) interleaved u/gate
    const float* __restrict__ conv_w, const float* __restrict__ conv_b,
    const float* __restrict__ Aa, const float* __restrict__ Bp, const float* __restrict__ Cp,
    unsigned short* __restrict__ yhi, unsigned short* __restrict__ ylo)
{
    const int NB = INNER / 256;  // 8
    int tid = threadIdx.x;
    int bi = blockIdx.x;
    int b  = bi / (NCHK * NB);
    int r  = bi % (NCHK * NB);
    int ch = r / NB;
    int n  = (r % NB) * 256 + tid;

    float4 w = *reinterpret_cast<const float4*>(&conv_w[n * 4]);
    float cb = conv_b[n];
    float An[16], Bn[16], Cn[16], st[16];
#pragma unroll
    for (int i = 0; i < 16; i += 4) {
        float4 va = *reinterpret_cast<const float4*>(&Aa[n * 16 + i]);
        float4 vb = *reinterpret_cast<const float4*>(&Bp[n * 16 + i]);
        float4 vc = *reinterpret_cast<const float4*>(&Cp[n * 16 + i]);
        An[i]=va.x; An[i+1]=va.y; An[i+2]=va.z; An[i+3]=va.w;
        Bn[i]=vb.x; Bn[i+1]=vb.y; Bn[i+2]=vb.z; Bn[i+3]=vb.w;
        Cn[i]=vc.x; Cn[i+1]=vc.y; Cn[i+2]=vc.z; Cn[i+3]=vc.w;
    }
#pragma unroll
    for (int s = 0; s < 16; ++s) st[s] = 0.f;

    int out0 = ch * CHUNK;
    int lstart = (out0 >= WARM) ? (out0 - WARM) : 0;
    float u0 = 0.f, u1 = 0.f, u2 = 0.f;
    const float* xb = xp + (size_t)b * LSEQ * NPROJ;
    size_t ybase = (size_t)b * LSEQ * INNER;

    for (int l = lstart; l < out0; l += 8) {
        float uv[8];
#pragma unroll
        for (int i = 0; i < 8; ++i)
            uv[i] = xb[(size_t)(l + i) * NPROJ + 2 * n];
#pragma unroll
        for (int i = 0; i < 8; ++i) {
            float ul = uv[i];
            float xc = cb + w.x * u0 + w.y * u1 + w.z * u2 + w.w * ul;
            u0 = u1; u1 = u2; u2 = ul;
            float d = 1.f / (1.f + __expf(-xc));
            float dxc = d * xc;
#pragma unroll
            for (int s = 0; s < 16; ++s)
                st[s] = (An[s] * d) * st[s] + Bn[s] * dxc;
        }
    }
    for (int lt = 0; lt < CHUNK; lt += 8) {
        float uv[8], gv[8];
#pragma unroll
        for (int i = 0; i < 8; ++i) {
            float2 ug = *reinterpret_cast<const float2*>(
                &xb[(size_t)(out0 + lt + i) * NPROJ + 2 * n]);
            uv[i] = ug.x; gv[i] = ug.y;
        }
#pragma unroll
        for (int i = 0; i < 8; ++i) {
            float ul = uv[i];
            float xc = cb + w.x * u0 + w.y * u1 + w.z * u2 + w.w * ul;
            u0 = u1; u1 = u2; u2 = ul;
            float d = 1.f / (1.f + __expf(-xc));
            float dxc = d * xc;
            float y0 = 0.f, y1 = 0.f, y2 = 0.f, y3 = 0.f;
#pragma unroll
            for (int s = 0; s < 16; s += 4) {
                st[s + 0] = (An[s + 0] * d) * st[s + 0] + Bn[s + 0] * dxc;
                st[s + 1] = (An[s + 1] * d) * st[s + 1] + Bn[s + 1] * dxc;
                st[s + 2] = (An[s + 2] * d) * st[s + 2] + Bn[s + 2] * dxc;
                st[s + 3] = (An[s + 3] * d) * st[s + 3] + Bn[s + 3] * dxc;
                y0 += st[s + 0] * Cn[s + 0];
                y1 += st[s + 1] * Cn[s + 1];
                y2 += st[s + 2] * Cn[s + 2];
                y3 += st[s + 3] * Cn[s + 3];
            }
            float y = (y0 + y1) + (y2 + y3);
            float g = 1.f / (1.f + __expf(-gv[i]));
            float o = y * g;
            size_t idx = ybase + (size_t)(out0 + lt + i) * INNER + n;
            unsigned short hh = tobf(o);
            yhi[idx] = hh;
            ylo[idx] = tobf(o - frombf(hh));
        }
    }
}

extern "C" void kernel_launch(void* const* d_in, const int* in_sizes, int n_in,
                              void* d_out, int out_size, void* d_ws, size_t ws_size,
                              hipStream_t stream) {
    const float* x      = (const float*)d_in[0];
    const float* W_in   = (const float*)d_in[1];
    const float* conv_w = (const float*)d_in[2];
    const float* conv_b = (const float*)d_in[3];
    const float* A      = (const float*)d_in[4];
    const float* Bp     = (const float*)d_in[5];
    const float* Cp     = (const float*)d_in[6];
    const float* W_out  = (const float*)d_in[8];
    float* out = (float*)d_out;

    char* ws = (char*)d_ws;
    // [0,32Mi): xp f32 (GEMM1 out / scan in); later aliased by Wo hi/lo splits
    // [32Mi,48Mi): W_in hi/lo (GEMM1 in); later aliased by yg hi/lo (scan out)
    float* xp           = (float*)ws;
    unsigned short* Whi = (unsigned short*)(ws + (32u << 20));
    unsigned short* Wlo = (unsigned short*)(ws + (40u << 20));
    unsigned short* yghi = Whi;
    unsigned short* yglo = Wlo;
    unsigned short* Wohi = (unsigned short*)ws;
    unsigned short* Wolo = (unsigned short*)(ws + (4u << 20));

    dim3 blk(256);
    splitbf_k<<<dim3((NPROJ * D_MODEL) / 1024), blk, 0, stream>>>(W_in, Whi, Wlo, NPROJ * D_MODEL);
    gemm_mfma<128, 128, MROWS, NPROJ, D_MODEL, true>
        <<<dim3(NPROJ / 128, MROWS / 128), blk, 0, stream>>>(x, nullptr, nullptr, Whi, Wlo, xp);
    scan_kernel<<<dim3(BSZ * NCHK * (INNER / 256)), blk, 0, stream>>>(
        xp, conv_w, conv_b, A, Bp, Cp, yghi, yglo);
    splitbf_k<<<dim3((D_MODEL * INNER) / 1024), blk, 0, stream>>>(W_out, Wohi, Wolo, D_MODEL * INNER);
    gemm_mfma<128, 64, MROWS, D_MODEL, INNER, false>
        <<<dim3(D_MODEL / 64, MROWS / 128), blk, 0, stream>>>(nullptr, yghi, yglo, Wohi, Wolo, out);
}

// Round 5
// 152.621 us; speedup vs baseline: 4.3300x; 1.0440x over previous
//
#include <hip/hip_runtime.h>
#include <hip/hip_bf16.h>

#define D_MODEL 1024
#define INNER   2048
#define NPROJ   4096   // 2*INNER
#define BSZ     2
#define LSEQ    1024
#define MROWS   (BSZ*LSEQ)  // 2048

#define CHUNK 32
#define WARM  48
#define NCHK  (LSEQ / CHUNK)   // 32

using short8   = __attribute__((ext_vector_type(8))) short;
using ushort8  = __attribute__((ext_vector_type(8))) unsigned short;
using f32x4    = __attribute__((ext_vector_type(4))) float;
typedef unsigned short ushort;

__device__ __forceinline__ ushort tobf(float x) {
    return (ushort)(__builtin_bit_cast(unsigned, x) >> 16);
}
__device__ __forceinline__ float frombf(ushort h) {
    return __builtin_bit_cast(float, ((unsigned)h) << 16);
}
__device__ __forceinline__ void glds16(const void* g, void* l) {
    __builtin_amdgcn_global_load_lds((const __attribute__((address_space(1))) void*)g,
                                     (__attribute__((address_space(3))) void*)l, 16, 0, 0);
}

// f32 row-major (N x K) -> bf16 hi/lo in FRAGMENT-LINEAR order:
// subtile (rt,kt) = 16 rows x 32 cols, stored as 64 lanes x 8 elems, where
// lane l = (k_chunk<<4)|row_in_subtile holds elems (row rt*16+(l&15), cols kt*32+(l>>4)*8 ..+8).
template<int K>
__global__ __launch_bounds__(256) void splitbf_frag(const float* __restrict__ in,
                                                    ushort* __restrict__ hi,
                                                    ushort* __restrict__ lo, int nchunks) {
    int c = blockIdx.x * 256 + threadIdx.x;   // one 8-elem chunk per thread
    if (c >= nchunks) return;
    int l = c & 63, sub = c >> 6;
    constexpr int KT = K / 32;
    int kt = sub % KT, rt = sub / KT;
    const float* src = in + (size_t)(rt * 16 + (l & 15)) * K + kt * 32 + (l >> 4) * 8;
    ushort8 h, lw;
#pragma unroll
    for (int j = 0; j < 8; ++j) {
        float x = src[j];
        h[j]  = tobf(x);
        lw[j] = tobf(x - frombf(h[j]));
    }
    *reinterpret_cast<ushort8*>(&hi[(size_t)c * 8]) = h;
    *reinterpret_cast<ushort8*>(&lo[(size_t)c * 8]) = lw;
}

// C[M,N] = A[M,K] * B[N,K]^T via bf16x3 MFMA (hi*hi + hi*lo + lo*hi).
// Operands pre-split in fragment-linear order; staged subtile-at-a-time by
// global_load_lds (linear LDS dest); ds_read_b128 is stride-1 (conflict-free).
template<int BM, int BN, int M, int N, int K, bool CONVA>
__global__ __launch_bounds__(256, 2) void gemm_mfma(
    const float* __restrict__ Af,
    const ushort* __restrict__ Agh, const ushort* __restrict__ Agl,
    const ushort* __restrict__ Bgh, const ushort* __restrict__ Bgl,
    float* __restrict__ C)
{
    constexpr int BK = 32;
    constexpr int NT = K / BK;
    constexpr int KT = K / 32;
    constexpr int FM = BM / 32;
    constexpr int FN = BN / 32;
    __shared__ ushort Ah[2][BM * 32], Al[2][BM * 32];
    __shared__ ushort Bh[2][BN * 32], Bl[2][BN * 32];

    const int tid = threadIdx.x;
    const int wid = tid >> 6, lane = tid & 63;
    const int lm = lane & 15, lk = lane >> 4;
    const int m0 = blockIdx.y * BM, n0 = blockIdx.x * BN;
    const int wm = (wid >> 1) * (BM / 2), wn = (wid & 1) * (BN / 2);

    f32x4 acc[FM][FN] = {};
    float areg[16];

    // stage one 16x32 subtile (1 KiB) per glds16 call; both sides linear.
    auto stage_frag = [&](const ushort* __restrict__ src, ushort* dst,
                          int rows, int rb, int t) {
        const int nsub = rows >> 4;
        for (int s = wid; s < nsub; s += 4) {
            const ushort* g = src + ((size_t)((rb >> 4) + s) * KT + t) * 512 + lane * 8;
            glds16(g, dst + s * 512);
        }
    };
    auto stageB = [&](int t, int b) {
        stage_frag(Bgh, &Bh[b][0], BN, n0, t);
        stage_frag(Bgl, &Bl[b][0], BN, n0, t);
    };
    auto stageA_glds = [&](int t, int b) {
        stage_frag(Agh, &Ah[b][0], BM, m0, t);
        stage_frag(Agl, &Al[b][0], BM, m0, t);
    };
    // CONVA: f32 A loaded to regs, split, written to LDS in fragment order.
    // thread t: subtile sub = t>>5, lanes l0=(t&31)*2, l0+1 (two rows, one k-chunk).
    auto stageA_load = [&](int t) {
        int sub = tid >> 5, l0 = (tid & 31) * 2;
        const float* p = Af + (size_t)(m0 + sub * 16 + (l0 & 15)) * K + t * BK + (l0 >> 4) * 8;
#pragma unroll
        for (int i = 0; i < 2; ++i) {   // two rows: l0 (even), l0+1
            const float* q = p + (size_t)i * K;
            float4 v0 = *reinterpret_cast<const float4*>(q);
            float4 v1 = *reinterpret_cast<const float4*>(q + 4);
            areg[i * 8 + 0] = v0.x; areg[i * 8 + 1] = v0.y;
            areg[i * 8 + 2] = v0.z; areg[i * 8 + 3] = v0.w;
            areg[i * 8 + 4] = v1.x; areg[i * 8 + 5] = v1.y;
            areg[i * 8 + 6] = v1.z; areg[i * 8 + 7] = v1.w;
        }
    };
    auto stageA_write = [&](int b) {
        int sub = tid >> 5, l0 = (tid & 31) * 2;
        ushort8 h[2], l8[2];
#pragma unroll
        for (int i = 0; i < 16; ++i) {
            ushort hh = tobf(areg[i]);
            h[i >> 3][i & 7]  = hh;
            l8[i >> 3][i & 7] = tobf(areg[i] - frombf(hh));
        }
        *reinterpret_cast<ushort8*>(&Ah[b][sub * 512 + l0 * 8])       = h[0];
        *reinterpret_cast<ushort8*>(&Ah[b][sub * 512 + (l0 + 1) * 8]) = h[1];
        *reinterpret_cast<ushort8*>(&Al[b][sub * 512 + l0 * 8])       = l8[0];
        *reinterpret_cast<ushort8*>(&Al[b][sub * 512 + (l0 + 1) * 8]) = l8[1];
    };
    auto compute = [&](int b) {
        short8 ah[FM], al[FM], bh[FN], bl[FN];
#pragma unroll
        for (int i = 0; i < FM; ++i) {
            int off = ((wm >> 4) + i) * 512 + lane * 8;
            ah[i] = *reinterpret_cast<const short8*>(&Ah[b][off]);
            al[i] = *reinterpret_cast<const short8*>(&Al[b][off]);
        }
#pragma unroll
        for (int j = 0; j < FN; ++j) {
            int off = ((wn >> 4) + j) * 512 + lane * 8;
            bh[j] = *reinterpret_cast<const short8*>(&Bh[b][off]);
            bl[j] = *reinterpret_cast<const short8*>(&Bl[b][off]);
        }
#pragma unroll
        for (int i = 0; i < FM; ++i)
#pragma unroll
            for (int j = 0; j < FN; ++j) {
                acc[i][j] = __builtin_amdgcn_mfma_f32_16x16x32_bf16(ah[i], bh[j], acc[i][j], 0, 0, 0);
                acc[i][j] = __builtin_amdgcn_mfma_f32_16x16x32_bf16(ah[i], bl[j], acc[i][j], 0, 0, 0);
                acc[i][j] = __builtin_amdgcn_mfma_f32_16x16x32_bf16(al[i], bh[j], acc[i][j], 0, 0, 0);
            }
    };

    stageB(0, 0);
    if constexpr (CONVA) { stageA_load(0); stageA_write(0); } else { stageA_glds(0, 0); }
    __syncthreads();

    int buf = 0;
    for (int t = 0; t < NT; ++t) {
        if (t + 1 < NT) {
            stageB(t + 1, buf ^ 1);
            if constexpr (CONVA) stageA_load(t + 1); else stageA_glds(t + 1, buf ^ 1);
        }
        compute(buf);
        if constexpr (CONVA) { if (t + 1 < NT) stageA_write(buf ^ 1); }
        __syncthreads();
        buf ^= 1;
    }

#pragma unroll
    for (int i = 0; i < FM; ++i)
#pragma unroll
        for (int j = 0; j < FN; ++j)
#pragma unroll
            for (int r = 0; r < 4; ++r) {
                int row = m0 + wm + i * 16 + lk * 4 + r;
                int col = n0 + wn + j * 16 + lm;
                C[(size_t)row * N + col] = acc[i][j][r];
            }
}

// Chunk-parallel fused conv + sigmoid + scan + gate; emits yg as bf16 hi/lo
// in fragment-linear order for GEMM2's A (K = INNER = 2048, KT = 64).
__global__ __launch_bounds__(256) void scan_kernel(
    const float* __restrict__ xp,
    const float* __restrict__ conv_w, const float* __restrict__ conv_b,
    const float* __restrict__ Aa, const float* __restrict__ Bp, const float* __restrict__ Cp,
    ushort* __restrict__ yhi, ushort* __restrict__ ylo)
{
    const int NB = INNER / 256;  // 8
    int tid = threadIdx.x;
    int bi = blockIdx.x;
    int b  = bi / (NCHK * NB);
    int r  = bi % (NCHK * NB);
    int ch = r / NB;
    int n  = (r % NB) * 256 + tid;

    float4 w = *reinterpret_cast<const float4*>(&conv_w[n * 4]);
    float cb = conv_b[n];
    float An[16], Bn[16], Cn[16], st[16];
#pragma unroll
    for (int i = 0; i < 16; i += 4) {
        float4 va = *reinterpret_cast<const float4*>(&Aa[n * 16 + i]);
        float4 vb = *reinterpret_cast<const float4*>(&Bp[n * 16 + i]);
        float4 vc = *reinterpret_cast<const float4*>(&Cp[n * 16 + i]);
        An[i]=va.x; An[i+1]=va.y; An[i+2]=va.z; An[i+3]=va.w;
        Bn[i]=vb.x; Bn[i+1]=vb.y; Bn[i+2]=vb.z; Bn[i+3]=vb.w;
        Cn[i]=vc.x; Cn[i+1]=vc.y; Cn[i+2]=vc.z; Cn[i+3]=vc.w;
    }
#pragma unroll
    for (int s = 0; s < 16; ++s) st[s] = 0.f;

    int out0 = ch * CHUNK;
    int lstart = (out0 >= WARM) ? (out0 - WARM) : 0;
    float u0 = 0.f, u1 = 0.f, u2 = 0.f;
    const float* xb = xp + (size_t)b * LSEQ * NPROJ;
    // per-thread constant part of the fragment index (col n of GEMM2's A)
    size_t fcol = (size_t)(n >> 5) * 512 + ((n >> 3) & 3) * 128 + (n & 7);

    for (int l = lstart; l < out0; l += 8) {
        float uv[8];
#pragma unroll
        for (int i = 0; i < 8; ++i)
            uv[i] = xb[(size_t)(l + i) * NPROJ + 2 * n];
#pragma unroll
        for (int i = 0; i < 8; ++i) {
            float ul = uv[i];
            float xc = cb + w.x * u0 + w.y * u1 + w.z * u2 + w.w * ul;
            u0 = u1; u1 = u2; u2 = ul;
            float d = 1.f / (1.f + __expf(-xc));
            float dxc = d * xc;
#pragma unroll
            for (int s = 0; s < 16; ++s)
                st[s] = (An[s] * d) * st[s] + Bn[s] * dxc;
        }
    }
    for (int lt = 0; lt < CHUNK; lt += 8) {
        float uv[8], gv[8];
#pragma unroll
        for (int i = 0; i < 8; ++i) {
            float2 ug = *reinterpret_cast<const float2*>(
                &xb[(size_t)(out0 + lt + i) * NPROJ + 2 * n]);
            uv[i] = ug.x; gv[i] = ug.y;
        }
#pragma unroll
        for (int i = 0; i < 8; ++i) {
            float ul = uv[i];
            float xc = cb + w.x * u0 + w.y * u1 + w.z * u2 + w.w * ul;
            u0 = u1; u1 = u2; u2 = ul;
            float d = 1.f / (1.f + __expf(-xc));
            float dxc = d * xc;
            float y0 = 0.f, y1 = 0.f, y2 = 0.f, y3 = 0.f;
#pragma unroll
            for (int s = 0; s < 16; s += 4) {
                st[s + 0] = (An[s + 0] * d) * st[s + 0] + Bn[s + 0] * dxc;
                st[s + 1] = (An[s + 1] * d) * st[s + 1] + Bn[s + 1] * dxc;
                st[s + 2] = (An[s + 2] * d) * st[s + 2] + Bn[s + 2] * dxc;
                st[s + 3] = (An[s + 3] * d) * st[s + 3] + Bn[s + 3] * dxc;
                y0 += st[s + 0] * Cn[s + 0];
                y1 += st[s + 1] * Cn[s + 1];
                y2 += st[s + 2] * Cn[s + 2];
                y3 += st[s + 3] * Cn[s + 3];
            }
            float y = (y0 + y1) + (y2 + y3);
            float g = 1.f / (1.f + __expf(-gv[i]));
            float o = y * g;
            int R = b * LSEQ + out0 + lt + i;                 // GEMM2 A-row
            size_t fi = ((size_t)(R >> 4) * 64) * 512 + fcol + (R & 15) * 8;
            ushort hh = tobf(o);
            yhi[fi] = hh;
            ylo[fi] = tobf(o - frombf(hh));
        }
    }
}

extern "C" void kernel_launch(void* const* d_in, const int* in_sizes, int n_in,
                              void* d_out, int out_size, void* d_ws, size_t ws_size,
                              hipStream_t stream) {
    const float* x      = (const float*)d_in[0];
    const float* W_in   = (const float*)d_in[1];
    const float* conv_w = (const float*)d_in[2];
    const float* conv_b = (const float*)d_in[3];
    const float* A      = (const float*)d_in[4];
    const float* Bp     = (const float*)d_in[5];
    const float* Cp     = (const float*)d_in[6];
    const float* W_out  = (const float*)d_in[8];
    float* out = (float*)d_out;

    char* ws = (char*)d_ws;
    // [0,32Mi): xp f32 (GEMM1 out / scan in); aliased later by W_out splits
    // [32Mi,48Mi): W_in hi/lo (GEMM1 B); aliased later by yg hi/lo (scan out)
    float* xp    = (float*)ws;
    ushort* Whi  = (ushort*)(ws + (32u << 20));
    ushort* Wlo  = (ushort*)(ws + (40u << 20));
    ushort* yghi = Whi;
    ushort* yglo = Wlo;
    ushort* Wohi = (ushort*)ws;
    ushort* Wolo = (ushort*)(ws + (4u << 20));

    dim3 blk(256);
    splitbf_frag<D_MODEL><<<dim3((NPROJ * D_MODEL / 8) / 256), blk, 0, stream>>>(
        W_in, Whi, Wlo, NPROJ * D_MODEL / 8);
    gemm_mfma<128, 128, MROWS, NPROJ, D_MODEL, true>
        <<<dim3(NPROJ / 128, MROWS / 128), blk, 0, stream>>>(x, nullptr, nullptr, Whi, Wlo, xp);
    scan_kernel<<<dim3(BSZ * NCHK * (INNER / 256)), blk, 0, stream>>>(
        xp, conv_w, conv_b, A, Bp, Cp, yghi, yglo);
    splitbf_frag<INNER><<<dim3((D_MODEL * INNER / 8) / 256), blk, 0, stream>>>(
        W_out, Wohi, Wolo, D_MODEL * INNER / 8);
    gemm_mfma<128, 64, MROWS, D_MODEL, INNER, false>
        <<<dim3(D_MODEL / 64, MROWS / 128), blk, 0, stream>>>(nullptr, yghi, yglo, Wohi, Wolo, out);
}